// Round 12
// baseline (75.637 us; speedup 1.0000x reference)
//
#include <hip/hip_runtime.h>
#include <math.h>

// KANConv2D via bf16 MFMA 16x16x32, R18 = R10/R17 main (verified best) +
// vectorized cvt kernel (8 elems/thread: f32x8 load -> bf16x8 store, 81
// blocks instead of 648 -> shorter ramp, 8x fewer index chains/stores).
// Ablation history: fusion x3 (R8 coop, R9/R12 in-reg, R14 flag-barrier) all
// lost; wave-cube re-cuts x3 (R11/R15/R16) all lost; B-prefetch (R13)
// neutral. R10's {1 B-frag x 4 A-frags -> 4 MFMA} + two-kernel skeleton is
// the empirical optimum; d_ws poison fill (~41us) is fixed harness overhead.
// Main: 196 blocks (4 b x 7x7 tiles of 8x8 px, M=64), 512 thr = 8 waves:
//   wave = (nq 0..3: oc quarter of 16) x (kh 0..1: K half). Each wave: 4
//   A-frags (16 rows each) x 36 k32-steps, 8 f32x4 accs; cross-wave K
//   reduction via LDS SoA; kh=0 waves do the epilogue. Base conv k-order =
//   tap*32 + c (tap-major): A read from raw-x halo xh, no im2col scatter.
// Frag maps (validated R1/R6/R7/R10/R17 + m89/m120):
//   A: m = lane&15 (+16f for frag f), k = (lane>>4)*8 + j
//   B: n = lane&15, k = (lane>>4)*8 + j
//   C/D: col = lane&15 = n, row = (lane>>4)*4 + reg (+16f for frag f).

typedef __attribute__((ext_vector_type(8))) short bf16x8;
typedef __attribute__((ext_vector_type(8))) float f32x8;
typedef __attribute__((ext_vector_type(4))) float f32x4;

#define MFMA16(a, b, c) __builtin_amdgcn_mfma_f32_16x16x32_bf16((a), (b), (c), 0, 0, 0)

__device__ __forceinline__ unsigned short f2bf(float f) {
    unsigned u = __builtin_bit_cast(unsigned, f);
    u = (u + 0x7fffu + ((u >> 16) & 1u)) >> 16;   // RNE
    return (unsigned short)u;
}

__device__ __forceinline__ void eval_bases(float v, float bs[8]) {
    #pragma unroll
    for (int i = 0; i < 8; ++i) bs[i] = 0.0f;
    // knots: t_g = (g-3)*0.4 - 1, support [-2.2, 2.2)
    float t = (v + 2.2f) * 2.5f;
    if (t >= 0.0f && t < 11.0f) {
        int j = (int)t;
        if (j > 10) j = 10;
        float knot = (float)(j - 3) * 0.4f - 1.0f;
        float u  = (v - knot) * 2.5f;
        float um = 1.0f - u;
        float u2 = u * u, u3 = u2 * u;
        const float s6 = 1.0f / 6.0f;
        float w0 = um * um * um * s6;
        float w1 = (3.0f * u3 - 6.0f * u2 + 4.0f) * s6;
        float w2 = (-3.0f * u3 + 3.0f * u2 + 3.0f * u + 1.0f) * s6;
        float w3 = u3 * s6;
        int i0 = j - 3;
        if (i0 >= 0)               bs[i0]     = w0;
        if (i0 + 1 >= 0 && i0 < 7) bs[i0 + 1] = w1;
        if (i0 + 2 >= 0 && i0 < 6) bs[i0 + 2] = w2;
        if (i0 + 3 <= 7)           bs[i0 + 3] = w3;
    }
}

// ---- pre-kernel (vectorized, 8 elems/thread): fp32 weights -> bf16 B-frags ----
// wst fragment v (v = t*64 + l, t 0..287): 8 consecutive floats of ws ->
//   wst[v*8 + j] = bf16(ws[oc*2304 + S*32 + (l>>4)*8 + j]),  S=t%72, nq=t/72
// wbt fragment w (w = t*64 + l, t 0..35): j-stride 9 (tap-major k = tap*32+c)
//   wbt[w*8 + j] = bf16(wb[oc*288 + ((l>>4)*8+j)*9 + s]),     s=t%9,  nq=t/9
__global__ __launch_bounds__(256)
void cvt_swz_kernel(const float* __restrict__ ws, const float* __restrict__ wb,
                    unsigned short* __restrict__ wst, unsigned short* __restrict__ wbt) {
    int v = blockIdx.x * 256 + threadIdx.x;        // 0..20735
    if (v < 18432) {
        int l = v & 63, t = v >> 6;                // t 0..287
        int S = t % 72, nq = t / 72;
        int oc = nq * 16 + (l & 15);
        f32x8 w8 = *reinterpret_cast<const f32x8*>(ws + oc * 2304 + S * 32 + (l >> 4) * 8);
        bf16x8 pk;
        #pragma unroll
        for (int j = 0; j < 8; ++j) pk[j] = (short)f2bf(w8[j]);
        *reinterpret_cast<bf16x8*>(wst + v * 8) = pk;
    } else {
        int v2 = v - 18432;                        // 0..2303
        if (v2 < 2304) {
            int l = v2 & 63, t = v2 >> 6;          // t 0..35
            int s = t % 9, nq = t / 9;
            int oc = nq * 16 + (l & 15);
            const float* src = wb + oc * 288 + (l >> 4) * 72 + s;
            bf16x8 pk;
            #pragma unroll
            for (int j = 0; j < 8; ++j) pk[j] = (short)f2bf(src[j * 9]);
            *reinterpret_cast<bf16x8*>(wbt + v2 * 8) = pk;
        }
    }
}

__global__ __launch_bounds__(512)
void kan_mfma_kernel(const float* __restrict__ x,
                     const float* __restrict__ sc,
                     const unsigned short* __restrict__ wst,
                     const unsigned short* __restrict__ wbt,
                     float* __restrict__ out) {
    // sb: bases [c 0..31][hp 0..99][8]   = 25600 us (51200 B)
    // xh: raw x [hp 0..99][40: 32 c+pad] =  4000 us ( 8000 B)  total 59200 B
    __shared__ unsigned short smem[29600];
    unsigned short* sb = smem;
    unsigned short* xh = smem + 25600;

    const int tid = threadIdx.x;
    const int bx  = blockIdx.x;              // 0..195
    const int b   = bx / 49;
    const int r   = bx - b * 49;
    const int ty  = r / 7;
    const int tx  = r - ty * 7;
    const int h0  = ty * 8, w0 = tx * 8;

    const int lane = tid & 63;
    const int wv   = tid >> 6;        // 0..7
    const int nq   = wv & 3;          // oc quarter (16 oc)
    const int kh   = wv >> 2;         // K half
    const int ml   = lane & 15;       // A row within frag / B,C col (oc)
    const int kg   = lane >> 4;       // k-group 0..3 within k32 step
    const int py0  = ml >> 3, px0 = ml & 7;   // frag-0 pixel (rows 0..15)

    // ---- phase 1: 3200 halo elems (10x10x32), batched loads, 1 store each ----
    float vv[7];
    #pragma unroll
    for (int j = 0; j < 7; ++j) {
        int i = tid + j * 512;        // 0..3583
        float val = 0.0f;
        if (i < 3200) {
            int c  = i / 100;
            int hp = i - c * 100;
            int hy = hp / 10;
            int hx = hp - hy * 10;
            int hh = h0 + hy - 1, ww = w0 + hx - 1;
            if ((unsigned)hh < 56u && (unsigned)ww < 56u)
                val = x[((b * 32 + c) * 56 + hh) * 56 + ww];
        }
        vv[j] = val;
    }
    #pragma unroll
    for (int j = 0; j < 7; ++j) {
        int i = tid + j * 512;
        if (i < 3200) {
            int c  = i / 100;
            int hp = i - c * 100;
            float bs[8];
            eval_bases(vv[j], bs);
            bf16x8 pk;
            #pragma unroll
            for (int j2 = 0; j2 < 8; ++j2) pk[j2] = (short)f2bf(bs[j2]);
            *reinterpret_cast<bf16x8*>(&sb[i * 8]) = pk;   // i = c*100+hp
            xh[hp * 40 + c] = f2bf(vv[j]);
        }
    }
    __syncthreads();

    // spline A offsets (ushort units): step S = 9g+u reads p = 4S + kg
    //   -> c = 4g + (4u+kg)/9, tap = (4u+kg)%9.  aoff is g-independent.
    int aoff[9];
    #pragma unroll
    for (int u = 0; u < 9; ++u) {
        int tt  = 4 * u + kg;         // 0..35
        int dc  = tt / 9;
        int tap = tt - dc * 9;
        int th  = tap / 3;
        int tw  = tap - th * 3;
        aoff[u] = (dc * 100 + (py0 + th) * 10 + (px0 + tw)) * 8;
    }

    f32x4 aS[4] = {{0,0,0,0},{0,0,0,0},{0,0,0,0},{0,0,0,0}};
    f32x4 aB[4] = {{0,0,0,0},{0,0,0,0},{0,0,0,0},{0,0,0,0}};

    // ---- spline GEMM: this wave's 36 k32-steps (S = kh*36 + g*9 + u) ----
    const unsigned short* bp = wst + ((nq * 72 + kh * 36) * 64 + lane) * 8;
    for (int g = 0; g < 4; ++g) {
        const int cbase = kh * 12800 + g * 3200;   // channel-quad base (us)
        #pragma unroll
        for (int u = 0; u < 9; ++u) {
            bf16x8 bw = *reinterpret_cast<const bf16x8*>(bp + (g * 9 + u) * 512);
            #pragma unroll
            for (int f = 0; f < 4; ++f) {
                bf16x8 a = *reinterpret_cast<const bf16x8*>(&sb[cbase + aoff[u] + f * 160]);
                aS[f] = MFMA16(a, bw, aS[f]);
            }
        }
    }

    // ---- base GEMM (tap-major): steps s: kh=0 -> 0..4, kh=1 -> 5..8 ----
    {
        const unsigned short* bbp = wbt + (nq * 9 * 64 + lane) * 8;
        const int sbeg = kh ? 5 : 0;
        const int send = kh ? 9 : 5;
        for (int s = sbeg; s < send; ++s) {
            int th = (s * 11) >> 5;           // s/3 for s in 0..8
            int tw = s - 3 * th;
            bf16x8 bw = *reinterpret_cast<const bf16x8*>(bbp + s * 512);
            int xa = ((py0 + th) * 10 + (px0 + tw)) * 40 + kg * 8;
            #pragma unroll
            for (int f = 0; f < 4; ++f) {     // frag f = +2 rows = +800 us
                bf16x8 a = *reinterpret_cast<const bf16x8*>(&xh[xa + f * 800]);
                aB[f] = MFMA16(a, bw, aB[f]);
            }
        }
    }

    // ---- cross-wave K reduction via LDS (SoA: [32 words][260], conflict-free) ----
    __syncthreads();                               // all sb/xh reads done
    float* red = reinterpret_cast<float*>(smem);   // 32*260*4 = 33280 B
    const int idx = nq * 64 + lane;                // 0..255, same for the kh pair
    if (kh) {
        #pragma unroll
        for (int f = 0; f < 4; ++f) {
            #pragma unroll
            for (int w = 0; w < 4; ++w) red[(f * 4 + w) * 260 + idx] = aS[f][w];
        }
        #pragma unroll
        for (int f = 0; f < 4; ++f) {
            #pragma unroll
            for (int w = 0; w < 4; ++w) red[((16 + f * 4) + w) * 260 + idx] = aB[f][w];
        }
    }
    __syncthreads();
    if (!kh) {
        #pragma unroll
        for (int f = 0; f < 4; ++f) {
            #pragma unroll
            for (int w = 0; w < 4; ++w) aS[f][w] += red[(f * 4 + w) * 260 + idx];
        }
        #pragma unroll
        for (int f = 0; f < 4; ++f) {
            #pragma unroll
            for (int w = 0; w < 4; ++w) aB[f][w] += red[((16 + f * 4) + w) * 260 + idx];
        }

        // ---- epilogue: row m = f*16 + kg*4 + reg -> py = f*2+(kg>>1), px = (kg&1)*4+reg
        const int oc  = nq * 16 + ml;
        const float scv = sc[oc];
        #pragma unroll
        for (int f = 0; f < 4; ++f) {
            const int py  = f * 2 + (kg >> 1);
            const int pxb = (kg & 1) * 4;
            float* ob = out + ((b * 64 + oc) * 56 + h0 + py) * 56 + w0 + pxb;
            f32x4 res;
            #pragma unroll
            for (int reg = 0; reg < 4; ++reg) {
                float bv = aB[f][reg];
                float si = bv / (1.0f + __expf(-bv));
                res[reg] = si + scv * aS[f][reg];
            }
            *reinterpret_cast<f32x4*>(ob) = res;
        }
    }
}

extern "C" void kernel_launch(void* const* d_in, const int* in_sizes, int n_in,
                              void* d_out, int out_size, void* d_ws, size_t ws_size,
                              hipStream_t stream) {
    const float* x  = (const float*)d_in[0];   // (4,32,56,56)
    const float* wb = (const float*)d_in[1];   // (64,32,3,3)
    const float* ws = (const float*)d_in[2];   // (64,288,8)
    const float* sc = (const float*)d_in[3];   // (64,)
    float* out = (float*)d_out;                // (4,64,56,56)

    unsigned short* wst = (unsigned short*)d_ws;   // 147456 bf16
    unsigned short* wbt = wst + 147456;            // 18432 bf16

    cvt_swz_kernel<<<81, 256, 0, stream>>>(ws, wb, wst, wbt);
    kan_mfma_kernel<<<196, 512, 0, stream>>>(x, sc, wst, wbt, out);
}